// Round 10
// baseline (306.772 us; speedup 1.0000x reference)
//
#include <hip/hip_runtime.h>
#include <stdint.h>

// Problem constants: B=8, T=1024, E=1024, H=16, D=64
#define BB 8
#define TT 1024
#define EE 1024
#define HH 16
#define DD 64

// log2(e)/8: folded into Q projection so attention uses exp2 directly
#define L2E8 0.18033688011112042f

typedef __attribute__((ext_vector_type(8))) __bf16 bf16x8;
typedef __attribute__((ext_vector_type(4))) float f32x4;
typedef __attribute__((ext_vector_type(4))) unsigned short ushort4v;
typedef __attribute__((ext_vector_type(4))) unsigned int uint4v;
typedef __attribute__((ext_vector_type(2))) unsigned int uint2v;

__device__ __forceinline__ unsigned short f2bf(float f) {
  unsigned int u = __float_as_uint(f);
  u += 0x7fffu + ((u >> 16) & 1u);   // RNE (finite data)
  return (unsigned short)(u >> 16);
}

// pack two f32 -> bf16x2 with round-half-up: 2 adds + 1 v_perm (vs ~8 ops RNE)
__device__ __forceinline__ unsigned int pk2t(float a, float b) {
  return __builtin_amdgcn_perm(__float_as_uint(b) + 0x8000u,
                               __float_as_uint(a) + 0x8000u, 0x07060302u);
}

__device__ __forceinline__ f32x4 mfma_16x16x32(bf16x8 a, bf16x8 b, f32x4 c) {
  return __builtin_amdgcn_mfma_f32_16x16x32_bf16(a, b, c, 0, 0, 0);
}

// async global->LDS, 16B per lane; LDS dest must be wave-uniform base + lane*16
__device__ __forceinline__ void async_ld16(const unsigned short* g, unsigned short* l) {
  __builtin_amdgcn_global_load_lds(
      (const __attribute__((address_space(1))) void*)g,
      (__attribute__((address_space(3))) void*)l, 16, 0, 0);
}

// -------------------- cast fp32 -> bf16 for 3 inputs + 4 weights --------------------
// HBM-bound (~26us, near floor). r8's in-proj fused cast spilled (148us); keep separate.
__global__ __launch_bounds__(256) void cast_all(
    const float* __restrict__ xq, const float* __restrict__ xk, const float* __restrict__ xv,
    const float* __restrict__ wq, const float* __restrict__ wk,
    const float* __restrict__ wv, const float* __restrict__ wo,
    unsigned short* __restrict__ ws) {
  int blk = blockIdx.x;
  const float* src; size_t dstoff; int rel;
  if (blk < 4096)       { src = xq; dstoff = 0;        rel = blk; }
  else if (blk < 8192)  { src = xk; dstoff = 8388608;  rel = blk - 4096; }
  else if (blk < 12288) { src = xv; dstoff = 16777216; rel = blk - 8192; }
  else if (blk < 12800) { src = wq; dstoff = 25165824; rel = blk - 12288; }
  else if (blk < 13312) { src = wk; dstoff = 26214400; rel = blk - 12800; }
  else if (blk < 13824) { src = wv; dstoff = 27262976; rel = blk - 13312; }
  else                  { src = wo; dstoff = 28311552; rel = blk - 13824; }
  size_t base = (size_t)rel * 2048 + (size_t)threadIdx.x * 8;
  float4 a = *(const float4*)(src + base);
  float4 b = *(const float4*)(src + base + 4);
  ushort4v o0, o1;
  o0.x = f2bf(a.x); o0.y = f2bf(a.y); o0.z = f2bf(a.z); o0.w = f2bf(a.w);
  o1.x = f2bf(b.x); o1.y = f2bf(b.y); o1.z = f2bf(b.z); o1.w = f2bf(b.w);
  *(ushort4v*)(ws + dstoff + base) = o0;
  *(ushort4v*)(ws + dstoff + base + 4) = o1;
}

// -------------------- fused Q/K/V projection --------------------
// r5 version verbatim (session best: 69us): 128x128, BK=64, counted-vmcnt dbuf
// schedule, T2 XOR-swizzle (conflicts 0), XCD-local n-major id map (FETCH 49MB).
// 1536 blocks, flat id: [0,512) Q, [512,1024) K, [1024,1536) V^T.
__global__ __launch_bounds__(256, 2) void fused_proj(
    const unsigned short* __restrict__ xq, const unsigned short* __restrict__ xk,
    const unsigned short* __restrict__ xv, const unsigned short* __restrict__ wq,
    const unsigned short* __restrict__ wk, const unsigned short* __restrict__ wv,
    const float* __restrict__ bq, const float* __restrict__ bk, const float* __restrict__ bv,
    unsigned short* __restrict__ Qb, unsigned short* __restrict__ Kb,
    unsigned short* __restrict__ Vtb) {
  const int id = blockIdx.x;
  const int tid = threadIdx.x;
  const int wave = tid >> 6, lane = tid & 63;
  const int quad = lane >> 4, l16 = lane & 15;
  const int wr = wave >> 1, wc = wave & 1;

  const unsigned short *A, *W;
  const float* bias;
  int mode, m0, n0;
  size_t zoff = 0;
  if (id < 512) {
    mode = 0; A = xq; W = wq; bias = bq;
    m0 = (id & 63) * 128; n0 = (id >> 6) * 128;          // n-major (XCD-local A)
  } else if (id < 1024) {
    int t = id - 512;
    mode = 1; A = xk; W = wk; bias = bk;
    m0 = (t & 63) * 128; n0 = (t >> 6) * 128;            // n-major
  } else {
    int t = id - 1024;
    int z = t >> 6;
    mode = 2; A = wv; W = xv + (size_t)z * 1048576; bias = bv;
    m0 = ((t >> 3) & 7) * 128; n0 = (t & 7) * 128;       // already XCD-local
    zoff = (size_t)z * 1048576;
  }

  __shared__ __align__(16) unsigned short As[2][128 * 64];
  __shared__ __align__(16) unsigned short Bs[2][128 * 64];

  const unsigned short* Wb = W + (size_t)n0 * 1024;

  f32x4 acc[4][4];
#pragma unroll
  for (int i = 0; i < 4; ++i)
#pragma unroll
    for (int j = 0; j < 4; ++j) acc[i][j] = (f32x4){0.f, 0.f, 0.f, 0.f};

  const int row_s = tid >> 3, c_s = tid & 7;
  const int swl = l16 & 7;           // read-side swizzle key (row&7 == l16&7)

  // stage tile kt into buffer sel: 8 async_ld16 per wave (vmcnt += 8)
  auto stage = [&](int sel, int kt) {
    const unsigned short* Akt = A + (size_t)m0 * 1024 + kt * 64;
    const unsigned short* Wkt = Wb + kt * 64;
#pragma unroll
    for (int i = 0; i < 4; ++i) {
      int g = i * 256 + tid;
      int row = row_s + i * 32;
      int gc = c_s ^ (row & 7);      // pre-swizzled global source chunk
      async_ld16(Akt + (size_t)row * 1024 + gc * 8, &As[sel][g * 8]);
      async_ld16(Wkt + (size_t)row * 1024 + gc * 8, &Bs[sel][g * 8]);
    }
  };

  stage(0, 0);                                   //  8 in flight
  stage(1, 1);                                   // 16 in flight
  asm volatile("s_waitcnt vmcnt(8)" ::: "memory");   // my buf0 loads landed
  __builtin_amdgcn_s_barrier();                  // everyone's buf0 landed -> ready

  for (int kt = 0; kt < 16; ++kt) {
    const int cur = kt & 1;
    // invariant: buf[cur] ready; buf[cur^1] loads (tile kt+1) in flight
#pragma unroll
    for (int ks = 0; ks < 2; ++ks) {
      bf16x8 af[4], bfv[4];
      const int sc = (ks * 4 + quad) ^ swl;      // swizzled LDS chunk slot
#pragma unroll
      for (int i = 0; i < 4; ++i)
        af[i] = *(const bf16x8*)(&As[cur][((wr * 64 + i * 16 + l16) * 8 + sc) * 8]);
#pragma unroll
      for (int j = 0; j < 4; ++j)
        bfv[j] = *(const bf16x8*)(&Bs[cur][((wc * 64 + j * 16 + l16) * 8 + sc) * 8]);
      __builtin_amdgcn_s_setprio(1);
#pragma unroll
      for (int i = 0; i < 4; ++i)
#pragma unroll
        for (int j = 0; j < 4; ++j) acc[i][j] = mfma_16x16x32(af[i], bfv[j], acc[i][j]);
      __builtin_amdgcn_s_setprio(0);
    }
    __builtin_amdgcn_s_barrier();                // B1: all waves done READING buf[cur]
    int ktc = kt + 2 > 15 ? 15 : kt + 2;         // clamp: tail re-stages tile 15 (never read)
    stage(cur, ktc);                             // overwrite buf[cur]; 8+8 in flight
    asm volatile("s_waitcnt vmcnt(8)" ::: "memory"); // tile kt+1 landed (new 8 in flight)
    __builtin_amdgcn_s_barrier();                // B2: buf[cur^1] collectively ready
  }

  if (mode == 2) {
    size_t base = zoff;
    const int nxor = ((((l16 >> 2) + 1) & 2) ? 12 : 0);
#pragma unroll
    for (int i = 0; i < 4; ++i)
#pragma unroll
      for (int r = 0; r < 4; ++r) {
        int m = m0 + wr * 64 + i * 16 + quad * 4 + r;
        float bm = bias[m];
#pragma unroll
        for (int j = 0; j < 4; ++j) {
          int n = (n0 + wc * 64 + j * 16 + l16) ^ nxor;
          Vtb[base + (size_t)m * 1024 + n] = f2bf(acc[i][j][r] + bm);
        }
      }
  } else {
    unsigned short* Out = (mode == 0) ? Qb : Kb;
    const float scale = (mode == 0) ? L2E8 : 1.0f;
#pragma unroll
    for (int j = 0; j < 4; ++j) {
      int n = n0 + wc * 64 + j * 16 + l16;
      float bn = bias[n];
      int h = n >> 6, d = n & 63;
#pragma unroll
      for (int i = 0; i < 4; ++i)
#pragma unroll
        for (int r = 0; r < 4; ++r) {
          int m = m0 + wr * 64 + i * 16 + quad * 4 + r;
          int b = m >> 10, t = m & 1023;
          float v = (acc[i][j][r] + bn) * scale;
          Out[((size_t)((b << 4) + h) * 1024 + t) * 64 + d] = f2bf(v);
        }
    }
  }
}

// -------------------- final GEMM: out = O @ Wo^T + bo (fp32 out) --------------------
// r9 version (proj-proven 128x128 body; grid (64,8) keeps A-panel siblings XCD-local).
__global__ __launch_bounds__(256, 2) void gemm_out(
    const unsigned short* __restrict__ A, const unsigned short* __restrict__ Wm,
    const float* __restrict__ bias, float* __restrict__ Cout) {
  const int tid = threadIdx.x;
  const int wave = tid >> 6, lane = tid & 63;
  const int quad = lane >> 4, l16 = lane & 15;
  const int wr = wave >> 1, wc = wave & 1;   // wave tile: 64m x 64n
  const int m0 = blockIdx.x * 128;
  const int n0 = blockIdx.y * 128;

  __shared__ __align__(16) unsigned short As[2][128 * 64];
  __shared__ __align__(16) unsigned short Bs[2][128 * 64];

  const unsigned short* Wb = Wm + (size_t)n0 * 1024;

  f32x4 acc[4][4];
#pragma unroll
  for (int i = 0; i < 4; ++i)
#pragma unroll
    for (int j = 0; j < 4; ++j) acc[i][j] = (f32x4){0.f, 0.f, 0.f, 0.f};

  const int row_s = tid >> 3, c_s = tid & 7;
  const int swl = l16 & 7;

  // stage K-tile kt (= head kt): A 128x64 (row stride 64) + B 128x64; 8 loads/thread
  auto stage = [&](int sel, int kt) {
    const unsigned short* Akt = A + (size_t)(m0 >> 10) * 1048576 +
                                (size_t)kt * 65536 + (size_t)(m0 & 1023) * 64;
    const unsigned short* Wkt = Wb + kt * 64;
#pragma unroll
    for (int i = 0; i < 4; ++i) {
      int g = i * 256 + tid;
      int row = row_s + i * 32;
      int gc = c_s ^ (row & 7);
      async_ld16(Akt + (size_t)row * 64 + gc * 8, &As[sel][g * 8]);
      async_ld16(Wkt + (size_t)row * 1024 + gc * 8, &Bs[sel][g * 8]);
    }
  };

  stage(0, 0);                                   //  8 in flight
  stage(1, 1);                                   // 16 in flight
  asm volatile("s_waitcnt vmcnt(8)" ::: "memory");
  __builtin_amdgcn_s_barrier();

  for (int kt = 0; kt < 16; ++kt) {
    const int cur = kt & 1;
#pragma unroll
    for (int ks = 0; ks < 2; ++ks) {
      bf16x8 af[4], bfv[4];
      const int sc = (ks * 4 + quad) ^ swl;
#pragma unroll
      for (int i = 0; i < 4; ++i)
        af[i] = *(const bf16x8*)(&As[cur][((wr * 64 + i * 16 + l16) * 8 + sc) * 8]);
#pragma unroll
      for (int j = 0; j < 4; ++j)
        bfv[j] = *(const bf16x8*)(&Bs[cur][((wc * 64 + j * 16 + l16) * 8 + sc) * 8]);
      __builtin_amdgcn_s_setprio(1);
#pragma unroll
      for (int i = 0; i < 4; ++i)
#pragma unroll
        for (int j = 0; j < 4; ++j) acc[i][j] = mfma_16x16x32(af[i], bfv[j], acc[i][j]);
      __builtin_amdgcn_s_setprio(0);
    }
    __builtin_amdgcn_s_barrier();                // B1: done reading buf[cur]
    int ktc = kt + 2 > 15 ? 15 : kt + 2;
    stage(cur, ktc);
    asm volatile("s_waitcnt vmcnt(8)" ::: "memory");
    __builtin_amdgcn_s_barrier();                // B2: buf[cur^1] ready
  }

#pragma unroll
  for (int j = 0; j < 4; ++j) {
    int n = n0 + wc * 64 + j * 16 + l16;
    float bn = bias[n];
#pragma unroll
    for (int i = 0; i < 4; ++i)
#pragma unroll
      for (int r = 0; r < 4; ++r) {
        int m = m0 + wr * 64 + i * 16 + quad * 4 + r;
        Cout[(size_t)m * 1024 + n] = acc[i][j][r] + bn;
      }
  }
}

// -------------------- attention: S^T form + dbuf LDS K/V + permlane swap --------------------
// Round-10 (two code-level fixes to the r5 structure; grid (128,16), 16 q-rows/wave):
// (a) DOUBLE-BUFFERED K/V with counted vmcnt (proj's proven schedule): the old loop
//     issued 4 global_load_lds then __syncthreads (vmcnt-0 drain) BEFORE compute --
//     raw L2/HBM latency exposed every iteration. Now: compute(buf cur) -> B1 ->
//     stage(cur, it+2) -> vmcnt(4) [tile it+1 landed] -> B2. LDS 16->32KB.
// (b) permlane32_swap replaces __shfl_xor(·,32): shfl lowers to ds_bpermute (LDS pipe
//     + lgkm waits inside the softmax chain). One swap(u01,u45) returns BOTH needed
//     words (T12): ret0 = lanes<32:u01(own) / lanes>=32:u45[lane-32] = av.x;
//     ret1 = lanes<32:u01[lane+32] / lanes>=32:u45(own) = av.z. 2 swaps replace
//     4 bpermutes + 4 selects per kv-half.
__global__ __launch_bounds__(256) void attn(
    const unsigned short* __restrict__ Q,   // (B,H,T,D), pre-scaled by log2e/8
    const unsigned short* __restrict__ K,   // (B,H,T,D)
    const unsigned short* __restrict__ Vt,  // (B,H,D,T), T pi-permuted per 32-block
    unsigned short* __restrict__ O) {       // (B,H,T,D)
  const int bh = blockIdx.x;
  const int tid = threadIdx.x;
  const int wave = tid >> 6, lane = tid & 63;
  const int quad = lane >> 4, l16 = lane & 15;
  const int q0 = blockIdx.y * 64 + wave * 16;
  const size_t bhTD = (size_t)bh * (TT * DD);
  const unsigned short* Qb = Q + bhTD;
  const unsigned short* Kb = K + bhTD;
  const unsigned short* Vb = Vt + bhTD;

  __shared__ __align__(16) unsigned short Ks[2][64 * 64];
  __shared__ __align__(16) unsigned short Vs[2][64 * 64];

  bf16x8 q_lo = *(const bf16x8*)(Qb + (size_t)(q0 + l16) * 64 + quad * 8);
  bf16x8 q_hi = *(const bf16x8*)(Qb + (size_t)(q0 + l16) * 64 + 32 + quad * 8);

  uint4v ou; ou.x = ou.y = ou.z = ou.w = 0x3F803F80u;   // bf16 1.0 x8
  const bf16x8 ones = __builtin_bit_cast(bf16x8, ou);

  f32x4 o_acc[4];
#pragma unroll
  for (int dd = 0; dd < 4; ++dd) o_acc[dd] = (f32x4){0.f, 0.f, 0.f, 0.f};
  f32x4 acc5 = (f32x4){0.f, 0.f, 0.f, 0.f};             // per-row sum of P-hat

  const int srow = tid >> 3;
  const int schunk = tid & 7;

  // stage kv-tile it2 into buffer sel: 4 async_ld16/thread (vmcnt += 4)
  auto stage = [&](int sel, int it2) {
    const int kv0 = it2 * 64;
#pragma unroll
    for (int i = 0; i < 2; ++i) {
      int row = srow + i * 32;
      int gc = schunk ^ (row & 7);
      async_ld16(Kb + (size_t)(kv0 + row) * 64 + gc * 8, &Ks[sel][(row * 8 + schunk) * 8]);
      async_ld16(Vb + (size_t)row * 1024 + kv0 + gc * 8, &Vs[sel][(row * 8 + schunk) * 8]);
    }
  };

  stage(0, 0);                                   // 4 in flight
  stage(1, 1);                                   // 8 in flight
  asm volatile("s_waitcnt vmcnt(4)" ::: "memory");   // tile 0 landed (mine)
  __builtin_amdgcn_s_barrier();                  // ...and everyone's

  for (int it = 0; it < 16; ++it) {
    const int cur = it & 1;
    // invariant: buf[cur] = tile it ready; buf[cur^1] loads (tile it+1) in flight

    // ---- phase 1: all S-MFMAs for both 32-kv halves ----
    f32x4 f[4];
#pragma unroll
    for (int c = 0; c < 2; ++c) {
      const int r0 = c * 32 + l16;
      const int r1 = r0 + 16;
      const int sw = r0 & 7;
      bf16x8 k00 = *(const bf16x8*)(&Ks[cur][(r0 * 8 + (quad ^ sw)) * 8]);
      bf16x8 k01 = *(const bf16x8*)(&Ks[cur][(r0 * 8 + ((quad + 4) ^ sw)) * 8]);
      bf16x8 k10 = *(const bf16x8*)(&Ks[cur][(r1 * 8 + (quad ^ sw)) * 8]);
      bf16x8 k11 = *(const bf16x8*)(&Ks[cur][(r1 * 8 + ((quad + 4) ^ sw)) * 8]);
      f32x4 a = (f32x4){0.f, 0.f, 0.f, 0.f};
      f32x4 b = (f32x4){0.f, 0.f, 0.f, 0.f};
      __builtin_amdgcn_s_setprio(1);
      a = mfma_16x16x32(k00, q_lo, a);
      a = mfma_16x16x32(k01, q_hi, a);
      b = mfma_16x16x32(k10, q_lo, b);
      b = mfma_16x16x32(k11, q_hi, b);
      __builtin_amdgcn_s_setprio(0);
      f[2 * c] = a; f[2 * c + 1] = b;
    }

    // ---- phase 2: exp2, pack, permlane-swap A-frag build, denom + PV MFMAs ----
#pragma unroll
    for (int c = 0; c < 2; ++c) {
      f32x4 f0 = f[2 * c], f1 = f[2 * c + 1];
      float p0 = __builtin_amdgcn_exp2f(f0[0]), p1 = __builtin_amdgcn_exp2f(f0[1]);
      float p2 = __builtin_amdgcn_exp2f(f0[2]), p3 = __builtin_amdgcn_exp2f(f0[3]);
      float p4 = __builtin_amdgcn_exp2f(f1[0]), p5 = __builtin_amdgcn_exp2f(f1[1]);
      float p6 = __builtin_amdgcn_exp2f(f1[2]), p7 = __builtin_amdgcn_exp2f(f1[3]);
      unsigned int u01 = pk2t(p0, p1), u23 = pk2t(p2, p3);
      unsigned int u45 = pk2t(p4, p5), u67 = pk2t(p6, p7);
      uint2v s0 = __builtin_amdgcn_permlane32_swap(u01, u45, false, false);
      uint2v s1 = __builtin_amdgcn_permlane32_swap(u23, u67, false, false);
      uint4v av;
      av.x = s0.x;   // lo: u01 own      | hi: u45 from lane-32
      av.y = s1.x;   // lo: u23 own      | hi: u67 from lane-32
      av.z = s0.y;   // lo: u01 lane+32  | hi: u45 own
      av.w = s1.y;   // lo: u23 lane+32  | hi: u67 own
      bf16x8 ap = __builtin_bit_cast(bf16x8, av);
      __builtin_amdgcn_s_setprio(1);
      acc5 = mfma_16x16x32(ap, ones, acc5);
#pragma unroll
      for (int dd = 0; dd < 4; ++dd) {
        int vr = dd * 16 + l16;
        bf16x8 bv = *(const bf16x8*)(&Vs[cur][(vr * 8 + ((c * 4 + quad) ^ (vr & 7))) * 8]);
        o_acc[dd] = mfma_16x16x32(ap, bv, o_acc[dd]);
      }
      __builtin_amdgcn_s_setprio(0);
    }

    __builtin_amdgcn_s_barrier();                // B1: all waves done reading buf[cur]
    int itc = it + 2 > 15 ? 15 : it + 2;         // clamp keeps vmcnt count invariant
    stage(cur, itc);                             // overwrite buf[cur]; 4+4 in flight
    asm volatile("s_waitcnt vmcnt(4)" ::: "memory"); // tile it+1 landed
    __builtin_amdgcn_s_barrier();                // B2: buf[cur^1] collectively ready
  }

#pragma unroll
  for (int r = 0; r < 4; ++r) {
    float invr = 1.f / acc5[r];    // acc5[r] = sum_k P[q=quad*4+r][k], same at every lane
    int trow = q0 + quad * 4 + r;
#pragma unroll
    for (int dd = 0; dd < 4; ++dd)
      O[bhTD + (size_t)trow * 64 + dd * 16 + l16] = f2bf(o_acc[dd][r] * invr);
  }
}

// -------------------- launch --------------------
extern "C" void kernel_launch(void* const* d_in, const int* in_sizes, int n_in,
                              void* d_out, int out_size, void* d_ws, size_t ws_size,
                              hipStream_t stream) {
  const float* xq = (const float*)d_in[0];
  const float* xk = (const float*)d_in[1];
  const float* xv = (const float*)d_in[2];
  const float* Wq = (const float*)d_in[3];
  const float* bq = (const float*)d_in[4];
  const float* Wk = (const float*)d_in[5];
  const float* bk = (const float*)d_in[6];
  const float* Wv = (const float*)d_in[7];
  const float* bv = (const float*)d_in[8];
  const float* Wo = (const float*)d_in[9];
  const float* bo = (const float*)d_in[10];

  unsigned short* ws = (unsigned short*)d_ws;
  unsigned short* xq_b = ws;                 // 8388608
  unsigned short* xk_b = ws + 8388608;
  unsigned short* xv_b = ws + 16777216;
  unsigned short* wq_b = ws + 25165824;      // 1048576 each
  unsigned short* wk_b = ws + 26214400;
  unsigned short* wv_b = ws + 27262976;
  unsigned short* wo_b = ws + 28311552;
  unsigned short* Qbuf = ws + 29360128;      // (B,H,T,D)
  unsigned short* Kbuf = ws + 37748736;      // (B,H,T,D)
  unsigned short* Vtb  = ws + 46137344;      // (B,H,D,T) pi-permuted
  unsigned short* Obuf = ws + 54525952;      // (B,H,T,D)

  cast_all<<<14336, 256, 0, stream>>>(xq, xk, xv, Wq, Wk, Wv, Wo, ws);

  fused_proj<<<1536, 256, 0, stream>>>(xq_b, xk_b, xv_b, wq_b, wk_b, wv_b,
                                       bq, bk, bv, Qbuf, Kbuf, Vtb);
  attn<<<dim3(128, 16), 256, 0, stream>>>(Qbuf, Kbuf, Vtb, Obuf);
  gemm_out<<<dim3(64, 8), 256, 0, stream>>>(Obuf, wo_b, bo, (float*)d_out);
}

// Round 11
// 300.310 us; speedup vs baseline: 1.0215x; 1.0215x over previous
//
#include <hip/hip_runtime.h>
#include <stdint.h>

// Problem constants: B=8, T=1024, E=1024, H=16, D=64
#define BB 8
#define TT 1024
#define EE 1024
#define HH 16
#define DD 64

// log2(e)/8: folded into Q projection so attention uses exp2 directly
#define L2E8 0.18033688011112042f

typedef __attribute__((ext_vector_type(8))) __bf16 bf16x8;
typedef __attribute__((ext_vector_type(4))) float f32x4;
typedef __attribute__((ext_vector_type(4))) unsigned short ushort4v;
typedef __attribute__((ext_vector_type(4))) unsigned int uint4v;
typedef __attribute__((ext_vector_type(2))) unsigned int uint2v;

__device__ __forceinline__ unsigned short f2bf(float f) {
  unsigned int u = __float_as_uint(f);
  u += 0x7fffu + ((u >> 16) & 1u);   // RNE (finite data)
  return (unsigned short)(u >> 16);
}

// pack two f32 -> bf16x2 with round-half-up: 2 adds + 1 v_perm (vs ~8 ops RNE)
__device__ __forceinline__ unsigned int pk2t(float a, float b) {
  return __builtin_amdgcn_perm(__float_as_uint(b) + 0x8000u,
                               __float_as_uint(a) + 0x8000u, 0x07060302u);
}

__device__ __forceinline__ f32x4 mfma_16x16x32(bf16x8 a, bf16x8 b, f32x4 c) {
  return __builtin_amdgcn_mfma_f32_16x16x32_bf16(a, b, c, 0, 0, 0);
}

// async global->LDS, 16B per lane; LDS dest must be wave-uniform base + lane*16
__device__ __forceinline__ void async_ld16(const unsigned short* g, unsigned short* l) {
  __builtin_amdgcn_global_load_lds(
      (const __attribute__((address_space(1))) void*)g,
      (__attribute__((address_space(3))) void*)l, 16, 0, 0);
}

// -------------------- cast fp32 -> bf16 for 3 inputs + 4 weights --------------------
// HBM-bound (~27us, near floor). r8's in-proj fused cast spilled (148us); keep separate.
__global__ __launch_bounds__(256) void cast_all(
    const float* __restrict__ xq, const float* __restrict__ xk, const float* __restrict__ xv,
    const float* __restrict__ wq, const float* __restrict__ wk,
    const float* __restrict__ wv, const float* __restrict__ wo,
    unsigned short* __restrict__ ws) {
  int blk = blockIdx.x;
  const float* src; size_t dstoff; int rel;
  if (blk < 4096)       { src = xq; dstoff = 0;        rel = blk; }
  else if (blk < 8192)  { src = xk; dstoff = 8388608;  rel = blk - 4096; }
  else if (blk < 12288) { src = xv; dstoff = 16777216; rel = blk - 8192; }
  else if (blk < 12800) { src = wq; dstoff = 25165824; rel = blk - 12288; }
  else if (blk < 13312) { src = wk; dstoff = 26214400; rel = blk - 12800; }
  else if (blk < 13824) { src = wv; dstoff = 27262976; rel = blk - 13312; }
  else                  { src = wo; dstoff = 28311552; rel = blk - 13824; }
  size_t base = (size_t)rel * 2048 + (size_t)threadIdx.x * 8;
  float4 a = *(const float4*)(src + base);
  float4 b = *(const float4*)(src + base + 4);
  ushort4v o0, o1;
  o0.x = f2bf(a.x); o0.y = f2bf(a.y); o0.z = f2bf(a.z); o0.w = f2bf(a.w);
  o1.x = f2bf(b.x); o1.y = f2bf(b.y); o1.z = f2bf(b.z); o1.w = f2bf(b.w);
  *(ushort4v*)(ws + dstoff + base) = o0;
  *(ushort4v*)(ws + dstoff + base + 4) = o1;
}

// -------------------- fused Q/K/V projection --------------------
// r5 version verbatim (session best: 69us): 128x128, BK=64, counted-vmcnt dbuf
// schedule, T2 XOR-swizzle (conflicts 0), XCD-local n-major id map (FETCH 49MB).
// 1536 blocks, flat id: [0,512) Q, [512,1024) K, [1024,1536) V^T.
__global__ __launch_bounds__(256, 2) void fused_proj(
    const unsigned short* __restrict__ xq, const unsigned short* __restrict__ xk,
    const unsigned short* __restrict__ xv, const unsigned short* __restrict__ wq,
    const unsigned short* __restrict__ wk, const unsigned short* __restrict__ wv,
    const float* __restrict__ bq, const float* __restrict__ bk, const float* __restrict__ bv,
    unsigned short* __restrict__ Qb, unsigned short* __restrict__ Kb,
    unsigned short* __restrict__ Vtb) {
  const int id = blockIdx.x;
  const int tid = threadIdx.x;
  const int wave = tid >> 6, lane = tid & 63;
  const int quad = lane >> 4, l16 = lane & 15;
  const int wr = wave >> 1, wc = wave & 1;

  const unsigned short *A, *W;
  const float* bias;
  int mode, m0, n0;
  size_t zoff = 0;
  if (id < 512) {
    mode = 0; A = xq; W = wq; bias = bq;
    m0 = (id & 63) * 128; n0 = (id >> 6) * 128;          // n-major (XCD-local A)
  } else if (id < 1024) {
    int t = id - 512;
    mode = 1; A = xk; W = wk; bias = bk;
    m0 = (t & 63) * 128; n0 = (t >> 6) * 128;            // n-major
  } else {
    int t = id - 1024;
    int z = t >> 6;
    mode = 2; A = wv; W = xv + (size_t)z * 1048576; bias = bv;
    m0 = ((t >> 3) & 7) * 128; n0 = (t & 7) * 128;       // already XCD-local
    zoff = (size_t)z * 1048576;
  }

  __shared__ __align__(16) unsigned short As[2][128 * 64];
  __shared__ __align__(16) unsigned short Bs[2][128 * 64];

  const unsigned short* Wb = W + (size_t)n0 * 1024;

  f32x4 acc[4][4];
#pragma unroll
  for (int i = 0; i < 4; ++i)
#pragma unroll
    for (int j = 0; j < 4; ++j) acc[i][j] = (f32x4){0.f, 0.f, 0.f, 0.f};

  const int row_s = tid >> 3, c_s = tid & 7;
  const int swl = l16 & 7;           // read-side swizzle key (row&7 == l16&7)

  // stage tile kt into buffer sel: 8 async_ld16 per wave (vmcnt += 8)
  auto stage = [&](int sel, int kt) {
    const unsigned short* Akt = A + (size_t)m0 * 1024 + kt * 64;
    const unsigned short* Wkt = Wb + kt * 64;
#pragma unroll
    for (int i = 0; i < 4; ++i) {
      int g = i * 256 + tid;
      int row = row_s + i * 32;
      int gc = c_s ^ (row & 7);      // pre-swizzled global source chunk
      async_ld16(Akt + (size_t)row * 1024 + gc * 8, &As[sel][g * 8]);
      async_ld16(Wkt + (size_t)row * 1024 + gc * 8, &Bs[sel][g * 8]);
    }
  };

  stage(0, 0);                                   //  8 in flight
  stage(1, 1);                                   // 16 in flight
  asm volatile("s_waitcnt vmcnt(8)" ::: "memory");   // my buf0 loads landed
  __builtin_amdgcn_s_barrier();                  // everyone's buf0 landed -> ready

  for (int kt = 0; kt < 16; ++kt) {
    const int cur = kt & 1;
    // invariant: buf[cur] ready; buf[cur^1] loads (tile kt+1) in flight
#pragma unroll
    for (int ks = 0; ks < 2; ++ks) {
      bf16x8 af[4], bfv[4];
      const int sc = (ks * 4 + quad) ^ swl;      // swizzled LDS chunk slot
#pragma unroll
      for (int i = 0; i < 4; ++i)
        af[i] = *(const bf16x8*)(&As[cur][((wr * 64 + i * 16 + l16) * 8 + sc) * 8]);
#pragma unroll
      for (int j = 0; j < 4; ++j)
        bfv[j] = *(const bf16x8*)(&Bs[cur][((wc * 64 + j * 16 + l16) * 8 + sc) * 8]);
      __builtin_amdgcn_s_setprio(1);
#pragma unroll
      for (int i = 0; i < 4; ++i)
#pragma unroll
        for (int j = 0; j < 4; ++j) acc[i][j] = mfma_16x16x32(af[i], bfv[j], acc[i][j]);
      __builtin_amdgcn_s_setprio(0);
    }
    __builtin_amdgcn_s_barrier();                // B1: all waves done READING buf[cur]
    int ktc = kt + 2 > 15 ? 15 : kt + 2;         // clamp: tail re-stages tile 15 (never read)
    stage(cur, ktc);                             // overwrite buf[cur]; 8+8 in flight
    asm volatile("s_waitcnt vmcnt(8)" ::: "memory"); // tile kt+1 landed (new 8 in flight)
    __builtin_amdgcn_s_barrier();                // B2: buf[cur^1] collectively ready
  }

  if (mode == 2) {
    size_t base = zoff;
    const int nxor = ((((l16 >> 2) + 1) & 2) ? 12 : 0);
#pragma unroll
    for (int i = 0; i < 4; ++i)
#pragma unroll
      for (int r = 0; r < 4; ++r) {
        int m = m0 + wr * 64 + i * 16 + quad * 4 + r;
        float bm = bias[m];
#pragma unroll
        for (int j = 0; j < 4; ++j) {
          int n = (n0 + wc * 64 + j * 16 + l16) ^ nxor;
          Vtb[base + (size_t)m * 1024 + n] = f2bf(acc[i][j][r] + bm);
        }
      }
  } else {
    unsigned short* Out = (mode == 0) ? Qb : Kb;
    const float scale = (mode == 0) ? L2E8 : 1.0f;
#pragma unroll
    for (int j = 0; j < 4; ++j) {
      int n = n0 + wc * 64 + j * 16 + l16;
      float bn = bias[n];
      int h = n >> 6, d = n & 63;
#pragma unroll
      for (int i = 0; i < 4; ++i)
#pragma unroll
        for (int r = 0; r < 4; ++r) {
          int m = m0 + wr * 64 + i * 16 + quad * 4 + r;
          int b = m >> 10, t = m & 1023;
          float v = (acc[i][j][r] + bn) * scale;
          Out[((size_t)((b << 4) + h) * 1024 + t) * 64 + d] = f2bf(v);
        }
    }
  }
}

// -------------------- final GEMM: out = O @ Wo^T + bo (fp32 out) --------------------
// r9 version (proj-proven 128x128 body; grid (64,8) keeps A-panel siblings XCD-local).
__global__ __launch_bounds__(256, 2) void gemm_out(
    const unsigned short* __restrict__ A, const unsigned short* __restrict__ Wm,
    const float* __restrict__ bias, float* __restrict__ Cout) {
  const int tid = threadIdx.x;
  const int wave = tid >> 6, lane = tid & 63;
  const int quad = lane >> 4, l16 = lane & 15;
  const int wr = wave >> 1, wc = wave & 1;   // wave tile: 64m x 64n
  const int m0 = blockIdx.x * 128;
  const int n0 = blockIdx.y * 128;

  __shared__ __align__(16) unsigned short As[2][128 * 64];
  __shared__ __align__(16) unsigned short Bs[2][128 * 64];

  const unsigned short* Wb = Wm + (size_t)n0 * 1024;

  f32x4 acc[4][4];
#pragma unroll
  for (int i = 0; i < 4; ++i)
#pragma unroll
    for (int j = 0; j < 4; ++j) acc[i][j] = (f32x4){0.f, 0.f, 0.f, 0.f};

  const int row_s = tid >> 3, c_s = tid & 7;
  const int swl = l16 & 7;

  // stage K-tile kt (= head kt): A 128x64 (row stride 64) + B 128x64; 8 loads/thread
  auto stage = [&](int sel, int kt) {
    const unsigned short* Akt = A + (size_t)(m0 >> 10) * 1048576 +
                                (size_t)kt * 65536 + (size_t)(m0 & 1023) * 64;
    const unsigned short* Wkt = Wb + kt * 64;
#pragma unroll
    for (int i = 0; i < 4; ++i) {
      int g = i * 256 + tid;
      int row = row_s + i * 32;
      int gc = c_s ^ (row & 7);
      async_ld16(Akt + (size_t)row * 64 + gc * 8, &As[sel][g * 8]);
      async_ld16(Wkt + (size_t)row * 1024 + gc * 8, &Bs[sel][g * 8]);
    }
  };

  stage(0, 0);                                   //  8 in flight
  stage(1, 1);                                   // 16 in flight
  asm volatile("s_waitcnt vmcnt(8)" ::: "memory");
  __builtin_amdgcn_s_barrier();

  for (int kt = 0; kt < 16; ++kt) {
    const int cur = kt & 1;
#pragma unroll
    for (int ks = 0; ks < 2; ++ks) {
      bf16x8 af[4], bfv[4];
      const int sc = (ks * 4 + quad) ^ swl;
#pragma unroll
      for (int i = 0; i < 4; ++i)
        af[i] = *(const bf16x8*)(&As[cur][((wr * 64 + i * 16 + l16) * 8 + sc) * 8]);
#pragma unroll
      for (int j = 0; j < 4; ++j)
        bfv[j] = *(const bf16x8*)(&Bs[cur][((wc * 64 + j * 16 + l16) * 8 + sc) * 8]);
      __builtin_amdgcn_s_setprio(1);
#pragma unroll
      for (int i = 0; i < 4; ++i)
#pragma unroll
        for (int j = 0; j < 4; ++j) acc[i][j] = mfma_16x16x32(af[i], bfv[j], acc[i][j]);
      __builtin_amdgcn_s_setprio(0);
    }
    __builtin_amdgcn_s_barrier();                // B1: done reading buf[cur]
    int ktc = kt + 2 > 15 ? 15 : kt + 2;
    stage(cur, ktc);
    asm volatile("s_waitcnt vmcnt(8)" ::: "memory");
    __builtin_amdgcn_s_barrier();                // B2: buf[cur^1] ready
  }

#pragma unroll
  for (int j = 0; j < 4; ++j) {
    int n = n0 + wc * 64 + j * 16 + l16;
    float bn = bias[n];
#pragma unroll
    for (int i = 0; i < 4; ++i)
#pragma unroll
      for (int r = 0; r < 4; ++r) {
        int m = m0 + wr * 64 + i * 16 + quad * 4 + r;
        Cout[(size_t)m * 1024 + n] = acc[i][j][r] + bn;
      }
  }
}

// -------------------- attention: S^T form + LDS-staged K/V tiles --------------------
// Round-11: r5/r9 staging structure restored EXACTLY (single-buffer 16KB LDS,
// syncthreads drain -- the measured-best residency point: r10's 32KB dbuf halved
// blocks/CU and cost 4.5us). ONLY isolated change kept from r10: permlane32_swap
// replaces __shfl_xor(·,32) (shfl lowers to ds_bpermute = LDS pipe + lgkm waits in
// the softmax chain; swap returns BOTH needed words, 2 swaps replace 4 bpermutes +
// 4 selects per kv-half; mapping machine-verified in r10, absmax identical).
__global__ __launch_bounds__(256) void attn(
    const unsigned short* __restrict__ Q,   // (B,H,T,D), pre-scaled by log2e/8
    const unsigned short* __restrict__ K,   // (B,H,T,D)
    const unsigned short* __restrict__ Vt,  // (B,H,D,T), T pi-permuted per 32-block
    unsigned short* __restrict__ O) {       // (B,H,T,D)
  const int bh = blockIdx.x;
  const int tid = threadIdx.x;
  const int wave = tid >> 6, lane = tid & 63;
  const int quad = lane >> 4, l16 = lane & 15;
  const int q0 = blockIdx.y * 64 + wave * 16;
  const size_t bhTD = (size_t)bh * (TT * DD);
  const unsigned short* Qb = Q + bhTD;
  const unsigned short* Kb = K + bhTD;
  const unsigned short* Vb = Vt + bhTD;

  __shared__ __align__(16) unsigned short Ks[64 * 64];
  __shared__ __align__(16) unsigned short Vs[64 * 64];

  bf16x8 q_lo = *(const bf16x8*)(Qb + (size_t)(q0 + l16) * 64 + quad * 8);
  bf16x8 q_hi = *(const bf16x8*)(Qb + (size_t)(q0 + l16) * 64 + 32 + quad * 8);

  uint4v ou; ou.x = ou.y = ou.z = ou.w = 0x3F803F80u;   // bf16 1.0 x8
  const bf16x8 ones = __builtin_bit_cast(bf16x8, ou);

  f32x4 o_acc[4];
#pragma unroll
  for (int dd = 0; dd < 4; ++dd) o_acc[dd] = (f32x4){0.f, 0.f, 0.f, 0.f};
  f32x4 acc5 = (f32x4){0.f, 0.f, 0.f, 0.f};             // per-row sum of P-hat

  const int srow = tid >> 3;
  const int schunk = tid & 7;

  for (int it = 0; it < 16; ++it) {
    const int kv0 = it * 64;
#pragma unroll
    for (int i = 0; i < 2; ++i) {
      int row = srow + i * 32;
      int gc = schunk ^ (row & 7);
      async_ld16(Kb + (size_t)(kv0 + row) * 64 + gc * 8, Ks + (row * 8 + schunk) * 8);
      async_ld16(Vb + (size_t)row * 1024 + kv0 + gc * 8, Vs + (row * 8 + schunk) * 8);
    }
    __syncthreads();

    // ---- phase 1: all S-MFMAs for both 32-kv halves ----
    f32x4 f[4];
#pragma unroll
    for (int c = 0; c < 2; ++c) {
      const int r0 = c * 32 + l16;
      const int r1 = r0 + 16;
      const int sw = r0 & 7;
      bf16x8 k00 = *(const bf16x8*)(Ks + (r0 * 8 + (quad ^ sw)) * 8);
      bf16x8 k01 = *(const bf16x8*)(Ks + (r0 * 8 + ((quad + 4) ^ sw)) * 8);
      bf16x8 k10 = *(const bf16x8*)(Ks + (r1 * 8 + (quad ^ sw)) * 8);
      bf16x8 k11 = *(const bf16x8*)(Ks + (r1 * 8 + ((quad + 4) ^ sw)) * 8);
      f32x4 a = (f32x4){0.f, 0.f, 0.f, 0.f};
      f32x4 b = (f32x4){0.f, 0.f, 0.f, 0.f};
      __builtin_amdgcn_s_setprio(1);
      a = mfma_16x16x32(k00, q_lo, a);
      a = mfma_16x16x32(k01, q_hi, a);
      b = mfma_16x16x32(k10, q_lo, b);
      b = mfma_16x16x32(k11, q_hi, b);
      __builtin_amdgcn_s_setprio(0);
      f[2 * c] = a; f[2 * c + 1] = b;
    }

    // ---- phase 2: exp2, pack, permlane-swap A-frag build, denom + PV MFMAs ----
#pragma unroll
    for (int c = 0; c < 2; ++c) {
      f32x4 f0 = f[2 * c], f1 = f[2 * c + 1];
      float p0 = __builtin_amdgcn_exp2f(f0[0]), p1 = __builtin_amdgcn_exp2f(f0[1]);
      float p2 = __builtin_amdgcn_exp2f(f0[2]), p3 = __builtin_amdgcn_exp2f(f0[3]);
      float p4 = __builtin_amdgcn_exp2f(f1[0]), p5 = __builtin_amdgcn_exp2f(f1[1]);
      float p6 = __builtin_amdgcn_exp2f(f1[2]), p7 = __builtin_amdgcn_exp2f(f1[3]);
      unsigned int u01 = pk2t(p0, p1), u23 = pk2t(p2, p3);
      unsigned int u45 = pk2t(p4, p5), u67 = pk2t(p6, p7);
      uint2v s0 = __builtin_amdgcn_permlane32_swap(u01, u45, false, false);
      uint2v s1 = __builtin_amdgcn_permlane32_swap(u23, u67, false, false);
      uint4v av;
      av.x = s0.x;   // lo: u01 own      | hi: u45 from lane-32
      av.y = s1.x;   // lo: u23 own      | hi: u67 from lane-32
      av.z = s0.y;   // lo: u01 lane+32  | hi: u45 own
      av.w = s1.y;   // lo: u23 lane+32  | hi: u67 own
      bf16x8 ap = __builtin_bit_cast(bf16x8, av);
      __builtin_amdgcn_s_setprio(1);
      acc5 = mfma_16x16x32(ap, ones, acc5);
#pragma unroll
      for (int dd = 0; dd < 4; ++dd) {
        int vr = dd * 16 + l16;
        bf16x8 bv = *(const bf16x8*)(Vs + (vr * 8 + ((c * 4 + quad) ^ (vr & 7))) * 8);
        o_acc[dd] = mfma_16x16x32(ap, bv, o_acc[dd]);
      }
      __builtin_amdgcn_s_setprio(0);
    }
    __syncthreads();
  }
#pragma unroll
  for (int r = 0; r < 4; ++r) {
    float invr = 1.f / acc5[r];    // acc5[r] = sum_k P[q=quad*4+r][k], same at every lane
    int trow = q0 + quad * 4 + r;
#pragma unroll
    for (int dd = 0; dd < 4; ++dd)
      O[bhTD + (size_t)trow * 64 + dd * 16 + l16] = f2bf(o_acc[dd][r] * invr);
  }
}

// -------------------- launch --------------------
extern "C" void kernel_launch(void* const* d_in, const int* in_sizes, int n_in,
                              void* d_out, int out_size, void* d_ws, size_t ws_size,
                              hipStream_t stream) {
  const float* xq = (const float*)d_in[0];
  const float* xk = (const float*)d_in[1];
  const float* xv = (const float*)d_in[2];
  const float* Wq = (const float*)d_in[3];
  const float* bq = (const float*)d_in[4];
  const float* Wk = (const float*)d_in[5];
  const float* bk = (const float*)d_in[6];
  const float* Wv = (const float*)d_in[7];
  const float* bv = (const float*)d_in[8];
  const float* Wo = (const float*)d_in[9];
  const float* bo = (const float*)d_in[10];

  unsigned short* ws = (unsigned short*)d_ws;
  unsigned short* xq_b = ws;                 // 8388608
  unsigned short* xk_b = ws + 8388608;
  unsigned short* xv_b = ws + 16777216;
  unsigned short* wq_b = ws + 25165824;      // 1048576 each
  unsigned short* wk_b = ws + 26214400;
  unsigned short* wv_b = ws + 27262976;
  unsigned short* wo_b = ws + 28311552;
  unsigned short* Qbuf = ws + 29360128;      // (B,H,T,D)
  unsigned short* Kbuf = ws + 37748736;      // (B,H,T,D)
  unsigned short* Vtb  = ws + 46137344;      // (B,H,D,T) pi-permuted
  unsigned short* Obuf = ws + 54525952;      // (B,H,T,D)

  cast_all<<<14336, 256, 0, stream>>>(xq, xk, xv, Wq, Wk, Wv, Wo, ws);

  fused_proj<<<1536, 256, 0, stream>>>(xq_b, xk_b, xv_b, wq_b, wk_b, wv_b,
                                       bq, bk, bv, Qbuf, Kbuf, Vtb);
  attn<<<dim3(128, 16), 256, 0, stream>>>(Qbuf, Kbuf, Vtb, Obuf);
  gemm_out<<<dim3(64, 8), 256, 0, stream>>>(Obuf, wo_b, bo, (float*)d_out);
}